// Round 14
// baseline (900.702 us; speedup 1.0000x reference)
//
#include <hip/hip_runtime.h>
#include <stdint.h>

typedef unsigned long long u64;

#define BB 8
#define NN 200000
#define CLS 20
#define K_PRE 500
#define MAXDET 300
#define SCORE_TH 0.05f
#define NMS_THR 0.5f

#define NBINS 512
#define CAND_CAP 4096

// fast path: fixed conservative collect threshold (uniform scores -> ~842/class >> 500)
// exactness for arbitrary inputs preserved by the IN-BLOCK histogram fallback in k_sortgather.
#define T_COL 0.996f

// collect geometry
#define CBLK 128
#define CTHR 256
#define IMG_F4 1000000
#define ITERS 4
#define BCAP 32

static constexpr float BINSCALE = (float)NBINS / 0.95f;

// ws layout (bytes) -- every region is written before read within one launch sequence
// (completion counters are zeroed by k_collect, node 1).
#define BCNT_OFF 0              // 1024*20*4 = 81920
#define BDATA_OFF 81920         // -> 5324800
#define SKEY_OFF 5324800        // -> 5980160
#define SBOX_OFF 5980160        // -> 7260160
#define SAR_OFF  7260160        // -> 7580160
#define KEEPI_OFF 7580160       // -> 7590400
#define SUP_OFF  7590400        // -> 12833280
#define CSELK_OFF 12833280      // -> 13217280
#define CSELA_OFF 13217280      // -> 13409280
#define KSEL_OFF 13409280       // -> 13409920
#define CNT_OFF  13409920       // 168*4 = 672 -> 13410592 (cnt_bc[160], cnt_img[8])

__device__ __forceinline__ int score_bin(float s) {
  int b = (int)((s - SCORE_TH) * BINSCALE);
  return b < 0 ? 0 : (b > NBINS - 1 ? NBINS - 1 : b);
}

__device__ __forceinline__ u64 shflx64(u64 v, int mask) {
  int hi = __shfl_xor((int)(unsigned)(v >> 32), mask, 64);
  int lo = __shfl_xor((int)(unsigned)(v & 0xFFFFFFFFu), mask, 64);
  return ((u64)(unsigned)hi << 32) | (unsigned)lo;
}

// ---- streaming pass: zero global atomics, LDS staging, per-block output region ----
__global__ __launch_bounds__(256) void k_collect(const float* __restrict__ cls,
                                                 int* __restrict__ bcnt, u64* __restrict__ bdata,
                                                 int* __restrict__ cnt) {
  __shared__ u64 ldata[CLS][BCAP];
  __shared__ int lcnt[CLS];
  int tid = threadIdx.x;
  if (tid < CLS) lcnt[tid] = 0;
  // zero the k_tail completion counters each launch (graph-replay determinism)
  if (blockIdx.x == 0 && blockIdx.y == 0) {
    for (int i = tid; i < 168; i += CTHR) cnt[i] = 0;
  }
  __syncthreads();
  int blk = blockIdx.x, b = blockIdx.y;
  const float4* p = (const float4*)(cls + (size_t)b * IMG_F4 * 4);
  int base0 = blk * (ITERS * 8 * CTHR);
  bool full = (base0 + ITERS * 8 * CTHR) <= IMG_F4;

#define PROC(v, fidx) { \
    float m4_ = fmaxf(fmaxf((v).x, (v).y), fmaxf((v).z, (v).w)); \
    if (m4_ > T_COL) { \
      float vv_[4] = {(v).x, (v).y, (v).z, (v).w}; \
      _Pragma("unroll") \
      for (int e_ = 0; e_ < 4; ++e_) { \
        if (vv_[e_] > T_COL) { \
          int g_ = (fidx) * 4 + e_; \
          int c_ = g_ % CLS, a_ = g_ / CLS; \
          int li_ = atomicAdd(&lcnt[c_], 1); \
          if (li_ < BCAP) \
            ldata[c_][li_] = ((u64)__float_as_uint(vv_[e_]) << 32) | (u64)(0xFFFFFFFFu - (unsigned)a_); \
        } \
      } \
    } }

  for (int it = 0; it < ITERS; ++it) {
    int i0 = base0 + it * (8 * CTHR) + tid;
    if (full) {
      float4 v0 = p[i0];
      float4 v1 = p[i0 + 1 * CTHR];
      float4 v2 = p[i0 + 2 * CTHR];
      float4 v3 = p[i0 + 3 * CTHR];
      float4 v4 = p[i0 + 4 * CTHR];
      float4 v5 = p[i0 + 5 * CTHR];
      float4 v6 = p[i0 + 6 * CTHR];
      float4 v7 = p[i0 + 7 * CTHR];
      PROC(v0, i0);
      PROC(v1, i0 + 1 * CTHR);
      PROC(v2, i0 + 2 * CTHR);
      PROC(v3, i0 + 3 * CTHR);
      PROC(v4, i0 + 4 * CTHR);
      PROC(v5, i0 + 5 * CTHR);
      PROC(v6, i0 + 6 * CTHR);
      PROC(v7, i0 + 7 * CTHR);
    } else {
      for (int k = 0; k < 8; ++k) {
        int idx = i0 + k * CTHR;
        if (idx < IMG_F4) { float4 v = p[idx]; PROC(v, idx); }
      }
    }
  }
#undef PROC
  __syncthreads();
  int w = tid >> 6, lane = tid & 63;
  int gblk = b * CBLK + blk;
  for (int c = w; c < CLS; c += 4) {
    int cnt2 = lcnt[c];
    if (lane == 0) bcnt[gblk * CLS + c] = cnt2;   // real count (may exceed BCAP -> fallback)
    int ns = cnt2 < BCAP ? cnt2 : BCAP;
    if (lane < ns) bdata[((size_t)(gblk * CLS + c)) * BCAP + lane] = ldata[c][lane];
  }
}

// ---- per-(b,c): validity check + gather (or in-block fallback) + exact top-500 sort ----
__global__ __launch_bounds__(1024) void k_sortgather(const float* __restrict__ boxes,
                                                     const float* __restrict__ cls,
                                                     const int* __restrict__ bcnt, const u64* __restrict__ bdata,
                                                     u64* __restrict__ skey, float4* __restrict__ sboxg,
                                                     float* __restrict__ sarg, u64* __restrict__ keepi) {
  __shared__ u64 keys[CAND_CAP];       // 32KB
  __shared__ int scnt[CBLK], soff[CBLK + 1];
  __shared__ int lh[NBINS];            // 2KB, fallback histogram
  __shared__ int sflag, sbin, scount;
  int bc = blockIdx.x;
  int b = bc / CLS, c = bc % CLS;
  int tid = threadIdx.x;
  if (tid == 0) { sflag = 0; scount = 0; }
  __syncthreads();
  if (tid < CBLK) {
    int v = bcnt[(b * CBLK + tid) * CLS + c];
    scnt[tid] = v;
    if (v > BCAP) atomicOr(&sflag, 1);
  }
  __syncthreads();
  // single-wave exclusive scan of 128 counts (2 per lane)
  if (tid < 64) {
    int a = scnt[2 * tid], bv = scnt[2 * tid + 1];
    int s = a + bv;
#pragma unroll
    for (int o = 1; o < 64; o <<= 1) {
      int t2 = __shfl_up(s, o, 64);
      if ((int)tid >= o) s += t2;
    }
    int excl = s - (a + bv);
    soff[2 * tid] = excl;
    soff[2 * tid + 1] = excl + a;
    if (tid == 63) soff[CBLK] = s;
  }
  __syncthreads();
  int total = soff[CBLK];
  bool fallback = (sflag != 0) || (total > CAND_CAP) || (total < K_PRE);
  int m;
  if (!fallback) {
    m = total;
    for (int e = tid; e < CBLK * BCAP; e += 1024) {
      int j = e >> 5, s = e & (BCAP - 1);
      if (s < scnt[j]) keys[soff[j] + s] = bdata[((size_t)((b * CBLK + j) * CLS + c)) * BCAP + s];
    }
  } else {
    // in-block exact fallback: histogram over this (b,c) column, threshold, collect.
    for (int i = tid; i < NBINS; i += 1024) lh[i] = 0;
    __syncthreads();
    for (int a = tid; a < NN; a += 1024) {
      float s = cls[((size_t)b * NN + a) * CLS + c];
      if (s > SCORE_TH) atomicAdd(&lh[score_bin(s)], 1);
    }
    __syncthreads();
    if (tid == 0) {
      int sum = 0, bin = 0;
      for (int i = NBINS - 1; i >= 0; --i) {
        sum += lh[i];
        if (sum >= K_PRE) { bin = i; break; }
      }
      sbin = bin;
    }
    __syncthreads();
    int bin = sbin;
    for (int a = tid; a < NN; a += 1024) {
      float s = cls[((size_t)b * NN + a) * CLS + c];
      if (s > SCORE_TH && score_bin(s) >= bin) {
        int pos = atomicAdd(&scount, 1);
        if (pos < CAND_CAP)
          keys[pos] = ((u64)__float_as_uint(s) << 32) | (u64)(0xFFFFFFFFu - (unsigned)a);
      }
    }
    __syncthreads();
    m = scount; if (m > CAND_CAP) m = CAND_CAP;
  }
  int nsort = 1024; while (nsort < m) nsort <<= 1;
  for (int i = m + tid; i < nsort; i += 1024) keys[i] = 0ULL;
  __syncthreads();

  if (nsort <= 1024) {
    // in-register bitonic, descending; shfl_xor for j<64, LDS exchange for j>=64
    u64 key = keys[tid];
    __syncthreads();
    for (int k2 = 2; k2 <= 1024; k2 <<= 1) {
      for (int j = k2 >> 1; j > 0; j >>= 1) {
        u64 other;
        if (j >= 64) {
          keys[tid] = key; __syncthreads();
          other = keys[tid ^ j]; __syncthreads();
        } else {
          other = shflx64(key, j);
        }
        bool keepmax = (((tid & k2) == 0) == ((tid & j) == 0));
        key = keepmax ? (key >= other ? key : other) : (key <= other ? key : other);
      }
    }
    keys[tid] = key;
    __syncthreads();
  } else {
    // LDS bitonic up to 4096 (rare)
    for (int k2 = 2; k2 <= nsort; k2 <<= 1) {
      for (int j = k2 >> 1; j > 0; j >>= 1) {
        for (int i = tid; i < nsort; i += 1024) {
          int ij = i ^ j;
          if (ij > i) {
            u64 a = keys[i], bv = keys[ij];
            bool up = ((i & k2) == 0);
            if (up ? (a < bv) : (a > bv)) { keys[i] = bv; keys[ij] = a; }
          }
        }
        __syncthreads();
      }
    }
  }

  // write sorted keys, fetch boxes, init keep-words from validity
  if (tid < 512) {
    u64 key = (tid < K_PRE) ? keys[tid] : 0ULL;
    skey[(size_t)bc * 512 + tid] = key;
    float sc = __uint_as_float((unsigned)(key >> 32));
    unsigned anchor = 0xFFFFFFFFu - (unsigned)(key & 0xFFFFFFFFu);
    bool val = (tid < K_PRE) && (sc > SCORE_TH);
    if (!val || anchor >= NN) anchor = 0;
    float4 bx = *(const float4*)(boxes + ((size_t)b * NN + anchor) * 4);
    if (tid < K_PRE) {
      sboxg[(size_t)bc * K_PRE + tid] = bx;
      sarg[(size_t)bc * K_PRE + tid] = fmaxf(bx.z - bx.x, 0.0f) * fmaxf(bx.w - bx.y, 0.0f);
    }
    u64 bm = __ballot(val);
    if ((tid & 63) == 0) keepi[bc * 8 + (tid >> 6)] = bm;
  }
}

// ---- sparse greedy diagonal + parallel apply (r13, unchanged logic) ----
template<int W>
__device__ __forceinline__ void sweep_block(u64 r0, u64 r1, u64 r2_, u64 r3, u64 r4, u64 r5,
                                            u64 r6, u64 r7, u64* keepw, int lane) {
  u64 diag = (W == 0) ? r0 : (W == 1) ? r1 : (W == 2) ? r2_ : (W == 3) ? r3
           : (W == 4) ? r4 : (W == 5) ? r5 : (W == 6) ? r6 : r7;
  u64 nz = __ballot(diag != 0ULL);
  u64 kw = keepw[W];
  u64 work = kw & nz;
  while (work) {
    int r = (int)__builtin_ctzll(work);
    unsigned lo = (unsigned)__builtin_amdgcn_readlane((int)(unsigned)(diag & 0xFFFFFFFFu), r);
    unsigned hi = (unsigned)__builtin_amdgcn_readlane((int)(unsigned)(diag >> 32), r);
    u64 dv = ((u64)hi << 32) | (u64)lo;
    kw &= ~dv;
    work &= work - 1ULL;
    work &= kw;
  }
  u64 msk = 0ULL - ((kw >> lane) & 1ULL);
#define RED(x) { x |= shflx64(x, 1); x |= shflx64(x, 2); x |= shflx64(x, 4); \
                 x |= shflx64(x, 8); x |= shflx64(x, 16); x |= shflx64(x, 32); }
  u64 a1 = r1 & msk, a2 = r2_ & msk, a3 = r3 & msk, a4 = r4 & msk,
      a5 = r5 & msk, a6 = r6 & msk, a7 = r7 & msk;
  if (W < 1) RED(a1);
  if (W < 2) RED(a2);
  if (W < 3) RED(a3);
  if (W < 4) RED(a4);
  if (W < 5) RED(a5);
  if (W < 6) RED(a6);
  if (W < 7) RED(a7);
#undef RED
  if (lane == 0) {
    keepw[W] = kw;
    if (W < 1) keepw[1] &= ~a1;
    if (W < 2) keepw[2] &= ~a2;
    if (W < 3) keepw[3] &= ~a3;
    if (W < 4) keepw[4] &= ~a4;
    if (W < 5) keepw[5] &= ~a5;
    if (W < 6) keepw[6] &= ~a6;
    if (W < 7) keepw[7] &= ~a7;
  }
}

// ---- fused tail: bitmat -> (last of 8) sweep -> (last of 20) per-image output.
//      grid (8, 160) x 1024. Release: per-thread __threadfence + __syncthreads
//      before tid0's device-scope atomicAdd; acquire: __threadfence after observing
//      the count. Output is independent of which block runs each phase. ----
__global__ __launch_bounds__(1024) void k_tail(const float4* __restrict__ sboxg,
                                               const float* __restrict__ sarg,
                                               const u64* __restrict__ keepi, const u64* __restrict__ skeyg,
                                               const float* __restrict__ boxes, u64* __restrict__ sup,
                                               u64* __restrict__ cselk, int* __restrict__ csela,
                                               int* __restrict__ ksel, int* __restrict__ cnt_bc,
                                               int* __restrict__ cnt_img, float* __restrict__ out) {
  __shared__ float4 rbox[64];
  __shared__ float rar[64];
  __shared__ u64 keepw[8];
  __shared__ int slast;
  __shared__ u64 skeym[CLS][MAXDET];  // 48KB
  __shared__ int skc[CLS];
  __shared__ u64 carr[1024];
  __shared__ int scond;
  __shared__ u64 sT;
  __shared__ int winc[MAXDET];
  __shared__ float winsc[MAXDET];

  int bc = blockIdx.y, rch = blockIdx.x;
  int b = bc / CLS, c = bc % CLS;
  int tid = threadIdx.x;
  int lane = tid & 63;

  // ---- phase A: bitmat chunk (64 rows x 512 cols, 32 ballots/thread) ----
  {
    int half = tid >> 9;
    int j = tid & 511;
    int w = (tid >> 6) & 7;
    if (tid < 64) {
      int r = rch * 64 + tid;
      int rc = r < K_PRE ? r : 0;
      rbox[tid] = sboxg[(size_t)bc * K_PRE + rc];
      rar[tid] = sarg[(size_t)bc * K_PRE + rc];
    }
    __syncthreads();
    int jc = j < K_PRE ? j : 0;
    float4 bj = sboxg[(size_t)bc * K_PRE + jc];
    float aj = sarg[(size_t)bc * K_PRE + jc];
    bool jval = j < K_PRE;
    int i0 = rch * 64 + half * 32;
    u64 myword = 0;
    for (int k = 0; k < 32; ++k) {
      int i = i0 + k;
      float4 bi = rbox[half * 32 + k];
      float ai = rar[half * 32 + k];
      float iw = fmaxf(fminf(bi.z, bj.z) - fmaxf(bi.x, bj.x), 0.0f);
      float ih = fmaxf(fminf(bi.w, bj.w) - fmaxf(bi.y, bj.y), 0.0f);
      float inter = iw * ih;
      float denom = fmaxf(ai + aj - inter, 1e-8f);
      bool pred = jval && (j > i) && (inter / denom > NMS_THR);
      u64 msk = __ballot(pred);
      if (k == lane) myword = msk;
    }
    int i = i0 + lane;
    if (lane < 32 && i < K_PRE) sup[(size_t)bc * 4096 + w * 512 + i] = myword;
  }
  // release + arrive
  __threadfence();
  __syncthreads();
  if (tid == 0) slast = atomicAdd(&cnt_bc[bc], 1);
  __syncthreads();
  if (slast != 7) return;
  __threadfence();  // acquire: other blocks' sup writes now visible

  // ---- phase B: sweep for bc (waves 0..7 hold rows in registers) ----
  {
    int wid = tid >> 6;
    u64 r0 = 0, r1 = 0, r2_ = 0, r3 = 0, r4 = 0, r5 = 0, r6 = 0, r7 = 0;
    if (wid < 8) {
      int row = wid * 64 + lane;
      const u64* sb = sup + (size_t)bc * 4096;
      r0 = sb[0 * 512 + row]; r1 = sb[1 * 512 + row];
      r2_ = sb[2 * 512 + row]; r3 = sb[3 * 512 + row];
      r4 = sb[4 * 512 + row]; r5 = sb[5 * 512 + row];
      r6 = sb[6 * 512 + row]; r7 = sb[7 * 512 + row];
    }
    if (tid < 8) keepw[tid] = keepi[bc * 8 + tid];
    __syncthreads();
    if (wid == 0) sweep_block<0>(r0, r1, r2_, r3, r4, r5, r6, r7, keepw, lane);
    __syncthreads();
    if (wid == 1) sweep_block<1>(r0, r1, r2_, r3, r4, r5, r6, r7, keepw, lane);
    __syncthreads();
    if (wid == 2) sweep_block<2>(r0, r1, r2_, r3, r4, r5, r6, r7, keepw, lane);
    __syncthreads();
    if (wid == 3) sweep_block<3>(r0, r1, r2_, r3, r4, r5, r6, r7, keepw, lane);
    __syncthreads();
    if (wid == 4) sweep_block<4>(r0, r1, r2_, r3, r4, r5, r6, r7, keepw, lane);
    __syncthreads();
    if (wid == 5) sweep_block<5>(r0, r1, r2_, r3, r4, r5, r6, r7, keepw, lane);
    __syncthreads();
    if (wid == 6) sweep_block<6>(r0, r1, r2_, r3, r4, r5, r6, r7, keepw, lane);
    __syncthreads();
    if (wid == 7) sweep_block<7>(r0, r1, r2_, r3, r4, r5, r6, r7, keepw, lane);
    __syncthreads();
    if (tid < 64) {
      int cnt = (tid < 8) ? __popcll(keepw[tid]) : 0;
      cnt += __shfl_xor(cnt, 1, 64);
      cnt += __shfl_xor(cnt, 2, 64);
      cnt += __shfl_xor(cnt, 4, 64);
      if (tid == 0) ksel[bc] = cnt > MAXDET ? MAXDET : cnt;
    }
    __syncthreads();
    if (tid < K_PRE) {
      int w = tid >> 6, bpos = tid & 63;
      u64 kw = keepw[w];
      if ((kw >> bpos) & 1ULL) {
        int rank = 0;
        for (int ww = 0; ww < w; ++ww) rank += __popcll(keepw[ww]);
        rank += __popcll(kw & ((1ULL << bpos) - 1ULL));
        if (rank < MAXDET) {
          u64 key = skeyg[(size_t)bc * 512 + tid];
          float sc = __uint_as_float((unsigned)(key >> 32));
          unsigned anchor = 0xFFFFFFFFu - (unsigned)(key & 0xFFFFFFFFu);
          if (anchor >= NN) anchor = 0;
          unsigned flat = (unsigned)(c * K_PRE + tid);
          cselk[(size_t)bc * MAXDET + rank] = ((u64)__float_as_uint(sc) << 32) | (u64)(0xFFFFFFFFu - flat);
          csela[(size_t)bc * MAXDET + rank] = (int)anchor;
        }
      }
    }
  }
  // release + arrive (per image)
  __threadfence();
  __syncthreads();
  if (tid == 0) slast = atomicAdd(&cnt_img[b], 1);
  __syncthreads();
  if (slast != CLS - 1) return;
  __threadfence();  // acquire: all 20 classes' cselk/csela/ksel visible

  // ---- phase C: per-image top-48-truncate + 1024 bitonic -> exact global top-300 ----
  if (tid < CLS) skc[tid] = ksel[b * CLS + tid];
  if (tid == 0) scond = 1;
  __syncthreads();
  for (int t = tid; t < CLS * MAXDET; t += 1024) {
    int cc = t / MAXDET, p = t % MAXDET;
    skeym[cc][p] = (p < skc[cc]) ? cselk[(size_t)(b * CLS + cc) * MAXDET + p] : 0ULL;
  }
  __syncthreads();
  {
    u64 v = 0ULL;
    if (tid < CLS * 48) {
      int cc = tid / 48, p = tid % 48;
      if (p < skc[cc]) v = skeym[cc][p];
    }
    carr[tid] = v;
  }
  __syncthreads();
  {
    u64 key = carr[tid];
    __syncthreads();
    for (int k2 = 2; k2 <= 1024; k2 <<= 1) {
      for (int j = k2 >> 1; j > 0; j >>= 1) {
        u64 other;
        if (j >= 64) {
          carr[tid] = key; __syncthreads();
          other = carr[tid ^ j]; __syncthreads();
        } else {
          other = shflx64(key, j);
        }
        bool keepmax = (((tid & k2) == 0) == ((tid & j) == 0));
        key = keepmax ? (key >= other ? key : other) : (key <= other ? key : other);
      }
    }
    carr[tid] = key;
    __syncthreads();
  }
  if (tid == 0) sT = carr[MAXDET - 1];
  __syncthreads();
  if (tid < CLS) {
    if (skc[tid] > 48 && skeym[tid][48] >= sT) atomicAnd(&scond, 0);
  }
  __syncthreads();

  if (scond) {
    for (int i = tid; i < MAXDET; i += 1024) {
      u64 kk = carr[i];
      float4 bx; float sc, lb;
      if (kk == 0ULL) {
        bx = make_float4(-1.f, -1.f, -1.f, -1.f); sc = -1.f; lb = -1.f;
      } else {
        unsigned flat = 0xFFFFFFFFu - (unsigned)(kk & 0xFFFFFFFFu);
        int cc = flat / K_PRE, pos = flat % K_PRE;
        u64 sk = skeyg[(size_t)(b * CLS + cc) * 512 + pos];
        unsigned anchor = 0xFFFFFFFFu - (unsigned)(sk & 0xFFFFFFFFu);
        if (anchor >= NN) anchor = 0;
        bx = *(const float4*)(boxes + ((size_t)b * NN + anchor) * 4);
        sc = __uint_as_float((unsigned)(kk >> 32));
        lb = (float)(cc - 1);  // reference: out_labels = fl - 1
      }
      *(float4*)(out + ((size_t)b * MAXDET + i) * 4) = bx;
      out[BB * MAXDET * 4 + b * MAXDET + i] = sc;
      out[BB * MAXDET * 4 + BB * MAXDET + b * MAXDET + i] = lb;
    }
    return;
  }

  // fallback: serial tournament (rare; exact)
  if (tid < 64) {
    int ln = tid;
    u64 cur = 0, nxt = 0; int p = 0, kc = 0;
    if (ln < CLS) {
      kc = skc[ln];
      cur = kc > 0 ? skeym[ln][0] : 0ULL;
      nxt = kc > 1 ? skeym[ln][1] : 0ULL;
    }
    for (int i = 0; i < MAXDET; ++i) {
      u64 mx = cur;
#pragma unroll
      for (int off = 16; off >= 1; off >>= 1) {
        unsigned hi = __shfl_xor((int)(unsigned)(mx >> 32), off, 32);
        unsigned lo = __shfl_xor((int)(unsigned)(mx & 0xFFFFFFFFu), off, 32);
        u64 o = ((u64)hi << 32) | lo;
        if (o > mx) mx = o;
      }
      if (mx != 0ULL && cur == mx) {
        winc[i] = (ln << 16) | p;
        winsc[i] = __uint_as_float((unsigned)(mx >> 32));
        ++p;
        cur = nxt;
        nxt = (p + 1 < kc) ? skeym[ln][p + 1] : 0ULL;
      }
      if (mx == 0ULL && ln == 0) winc[i] = -1;
    }
  }
  __syncthreads();
  for (int i = tid; i < MAXDET; i += 1024) {
    int wc = winc[i];
    float4 bx; float sc, lb;
    if (wc < 0) {
      bx = make_float4(-1.f, -1.f, -1.f, -1.f); sc = -1.f; lb = -1.f;
    } else {
      int cc = wc >> 16, p = wc & 0xFFFF;
      int anchor = csela[(size_t)(b * CLS + cc) * MAXDET + p];
      bx = *(const float4*)(boxes + ((size_t)b * NN + anchor) * 4);
      sc = winsc[i];
      lb = (float)(cc - 1);
    }
    *(float4*)(out + ((size_t)b * MAXDET + i) * 4) = bx;
    out[BB * MAXDET * 4 + b * MAXDET + i] = sc;
    out[BB * MAXDET * 4 + BB * MAXDET + b * MAXDET + i] = lb;
  }
}

extern "C" void kernel_launch(void* const* d_in, const int* in_sizes, int n_in,
                              void* d_out, int out_size, void* d_ws, size_t ws_size,
                              hipStream_t stream) {
  (void)in_sizes; (void)n_in; (void)out_size; (void)ws_size;
  const float* boxes = (const float*)d_in[0];
  const float* cls = (const float*)d_in[1];
  float* out = (float*)d_out;
  char* ws = (char*)d_ws;
  int* bcnt   = (int*)(ws + BCNT_OFF);
  u64* bdata  = (u64*)(ws + BDATA_OFF);
  u64* skey   = (u64*)(ws + SKEY_OFF);
  float4* sboxg = (float4*)(ws + SBOX_OFF);
  float* sarg = (float*)(ws + SAR_OFF);
  u64* keepi  = (u64*)(ws + KEEPI_OFF);
  u64* sup    = (u64*)(ws + SUP_OFF);
  u64* cselk  = (u64*)(ws + CSELK_OFF);
  int* csela  = (int*)(ws + CSELA_OFF);
  int* ksel   = (int*)(ws + KSEL_OFF);
  int* cnt    = (int*)(ws + CNT_OFF);   // cnt_bc[160], cnt_img[8]

  k_collect<<<dim3(CBLK, BB), CTHR, 0, stream>>>(cls, bcnt, bdata, cnt);
  k_sortgather<<<BB * CLS, 1024, 0, stream>>>(boxes, cls, bcnt, bdata, skey, sboxg, sarg, keepi);
  k_tail<<<dim3(8, BB * CLS), 1024, 0, stream>>>(sboxg, sarg, keepi, skey, boxes, sup,
                                                 cselk, csela, ksel, cnt, cnt + 160, out);
}

// Round 15
// 96.606 us; speedup vs baseline: 9.3234x; 9.3234x over previous
//
#include <hip/hip_runtime.h>
#include <stdint.h>

typedef unsigned long long u64;

#define BB 8
#define NN 200000
#define CLS 20
#define K_PRE 500
#define MAXDET 300
#define SCORE_TH 0.05f
#define NMS_THR 0.5f

#define NBINS 512
#define CAND_CAP 4096

// fast path: fixed conservative collect threshold (uniform scores -> ~842/class >> 500)
// exactness for arbitrary inputs preserved by the IN-BLOCK histogram fallback in k_sortgather.
#define T_COL 0.996f

// collect geometry
#define CBLK 128
#define CTHR 256
#define IMG_F4 1000000
#define ITERS 4
#define BCAP 32

static constexpr float BINSCALE = (float)NBINS / 0.95f;

// ws layout (bytes) -- NO region is read before being written within one launch sequence,
// so no memset node is needed. (sup rows 500..511 are read uninitialized but always
// masked by zero keep-bits -> deterministic output.)
#define BCNT_OFF 0              // 1024*20*4 = 81920
#define BDATA_OFF 81920         // -> 5324800
#define SKEY_OFF 5324800        // -> 5980160
#define SBOX_OFF 5980160        // -> 7260160
#define SAR_OFF  7260160        // -> 7580160
#define KEEPI_OFF 7580160       // -> 7590400
#define SUP_OFF  7590400        // -> 12833280
#define CSELK_OFF 12833280      // -> 13217280
#define CSELA_OFF 13217280      // -> 13409280
#define KSEL_OFF 13409280       // -> 13409920

__device__ __forceinline__ int score_bin(float s) {
  int b = (int)((s - SCORE_TH) * BINSCALE);
  return b < 0 ? 0 : (b > NBINS - 1 ? NBINS - 1 : b);
}

__device__ __forceinline__ u64 shflx64(u64 v, int mask) {
  int hi = __shfl_xor((int)(unsigned)(v >> 32), mask, 64);
  int lo = __shfl_xor((int)(unsigned)(v & 0xFFFFFFFFu), mask, 64);
  return ((u64)(unsigned)hi << 32) | (unsigned)lo;
}

// ---- streaming pass: zero global atomics, LDS staging, per-block output region ----
__global__ __launch_bounds__(256) void k_collect(const float* __restrict__ cls,
                                                 int* __restrict__ bcnt, u64* __restrict__ bdata) {
  __shared__ u64 ldata[CLS][BCAP];
  __shared__ int lcnt[CLS];
  int tid = threadIdx.x;
  if (tid < CLS) lcnt[tid] = 0;
  __syncthreads();
  int blk = blockIdx.x, b = blockIdx.y;
  const float4* p = (const float4*)(cls + (size_t)b * IMG_F4 * 4);
  int base0 = blk * (ITERS * 8 * CTHR);
  bool full = (base0 + ITERS * 8 * CTHR) <= IMG_F4;

#define PROC(v, fidx) { \
    float m4_ = fmaxf(fmaxf((v).x, (v).y), fmaxf((v).z, (v).w)); \
    if (m4_ > T_COL) { \
      float vv_[4] = {(v).x, (v).y, (v).z, (v).w}; \
      _Pragma("unroll") \
      for (int e_ = 0; e_ < 4; ++e_) { \
        if (vv_[e_] > T_COL) { \
          int g_ = (fidx) * 4 + e_; \
          int c_ = g_ % CLS, a_ = g_ / CLS; \
          int li_ = atomicAdd(&lcnt[c_], 1); \
          if (li_ < BCAP) \
            ldata[c_][li_] = ((u64)__float_as_uint(vv_[e_]) << 32) | (u64)(0xFFFFFFFFu - (unsigned)a_); \
        } \
      } \
    } }

  for (int it = 0; it < ITERS; ++it) {
    int i0 = base0 + it * (8 * CTHR) + tid;
    if (full) {
      float4 v0 = p[i0];
      float4 v1 = p[i0 + 1 * CTHR];
      float4 v2 = p[i0 + 2 * CTHR];
      float4 v3 = p[i0 + 3 * CTHR];
      float4 v4 = p[i0 + 4 * CTHR];
      float4 v5 = p[i0 + 5 * CTHR];
      float4 v6 = p[i0 + 6 * CTHR];
      float4 v7 = p[i0 + 7 * CTHR];
      PROC(v0, i0);
      PROC(v1, i0 + 1 * CTHR);
      PROC(v2, i0 + 2 * CTHR);
      PROC(v3, i0 + 3 * CTHR);
      PROC(v4, i0 + 4 * CTHR);
      PROC(v5, i0 + 5 * CTHR);
      PROC(v6, i0 + 6 * CTHR);
      PROC(v7, i0 + 7 * CTHR);
    } else {
      for (int k = 0; k < 8; ++k) {
        int idx = i0 + k * CTHR;
        if (idx < IMG_F4) { float4 v = p[idx]; PROC(v, idx); }
      }
    }
  }
#undef PROC
  __syncthreads();
  int w = tid >> 6, lane = tid & 63;
  int gblk = b * CBLK + blk;
  for (int c = w; c < CLS; c += 4) {
    int cnt = lcnt[c];
    if (lane == 0) bcnt[gblk * CLS + c] = cnt;   // real count (may exceed BCAP -> fallback)
    int ns = cnt < BCAP ? cnt : BCAP;
    if (lane < ns) bdata[((size_t)(gblk * CLS + c)) * BCAP + lane] = ldata[c][lane];
  }
}

// ---- per-(b,c): validity check + gather (or in-block fallback) + exact top-500 sort ----
__global__ __launch_bounds__(1024) void k_sortgather(const float* __restrict__ boxes,
                                                     const float* __restrict__ cls,
                                                     const int* __restrict__ bcnt, const u64* __restrict__ bdata,
                                                     u64* __restrict__ skey, float4* __restrict__ sboxg,
                                                     float* __restrict__ sarg, u64* __restrict__ keepi) {
  __shared__ u64 keys[CAND_CAP];       // 32KB
  __shared__ int scnt[CBLK], soff[CBLK + 1];
  __shared__ int lh[NBINS];            // 2KB, fallback histogram
  __shared__ int sflag, sbin, scount;
  int bc = blockIdx.x;
  int b = bc / CLS, c = bc % CLS;
  int tid = threadIdx.x;
  if (tid == 0) { sflag = 0; scount = 0; }
  __syncthreads();
  if (tid < CBLK) {
    int v = bcnt[(b * CBLK + tid) * CLS + c];
    scnt[tid] = v;
    if (v > BCAP) atomicOr(&sflag, 1);
  }
  __syncthreads();
  // single-wave exclusive scan of 128 counts (2 per lane)
  if (tid < 64) {
    int a = scnt[2 * tid], bv = scnt[2 * tid + 1];
    int s = a + bv;
#pragma unroll
    for (int o = 1; o < 64; o <<= 1) {
      int t2 = __shfl_up(s, o, 64);
      if ((int)tid >= o) s += t2;
    }
    int excl = s - (a + bv);
    soff[2 * tid] = excl;
    soff[2 * tid + 1] = excl + a;
    if (tid == 63) soff[CBLK] = s;
  }
  __syncthreads();
  int total = soff[CBLK];
  bool fallback = (sflag != 0) || (total > CAND_CAP) || (total < K_PRE);
  int m;
  if (!fallback) {
    m = total;
    for (int e = tid; e < CBLK * BCAP; e += 1024) {
      int j = e >> 5, s = e & (BCAP - 1);
      if (s < scnt[j]) keys[soff[j] + s] = bdata[((size_t)((b * CBLK + j) * CLS + c)) * BCAP + s];
    }
  } else {
    // in-block exact fallback: histogram over this (b,c) column, threshold, collect.
    for (int i = tid; i < NBINS; i += 1024) lh[i] = 0;
    __syncthreads();
    for (int a = tid; a < NN; a += 1024) {
      float s = cls[((size_t)b * NN + a) * CLS + c];
      if (s > SCORE_TH) atomicAdd(&lh[score_bin(s)], 1);
    }
    __syncthreads();
    if (tid == 0) {
      int sum = 0, bin = 0;
      for (int i = NBINS - 1; i >= 0; --i) {
        sum += lh[i];
        if (sum >= K_PRE) { bin = i; break; }
      }
      sbin = bin;
    }
    __syncthreads();
    int bin = sbin;
    for (int a = tid; a < NN; a += 1024) {
      float s = cls[((size_t)b * NN + a) * CLS + c];
      if (s > SCORE_TH && score_bin(s) >= bin) {
        int pos = atomicAdd(&scount, 1);
        if (pos < CAND_CAP)
          keys[pos] = ((u64)__float_as_uint(s) << 32) | (u64)(0xFFFFFFFFu - (unsigned)a);
      }
    }
    __syncthreads();
    m = scount; if (m > CAND_CAP) m = CAND_CAP;
  }
  int nsort = 1024; while (nsort < m) nsort <<= 1;
  for (int i = m + tid; i < nsort; i += 1024) keys[i] = 0ULL;
  __syncthreads();

  if (nsort <= 1024) {
    // in-register bitonic, descending; shfl_xor for j<64, LDS exchange for j>=64
    u64 key = keys[tid];
    __syncthreads();
    for (int k2 = 2; k2 <= 1024; k2 <<= 1) {
      for (int j = k2 >> 1; j > 0; j >>= 1) {
        u64 other;
        if (j >= 64) {
          keys[tid] = key; __syncthreads();
          other = keys[tid ^ j]; __syncthreads();
        } else {
          other = shflx64(key, j);
        }
        bool keepmax = (((tid & k2) == 0) == ((tid & j) == 0));
        key = keepmax ? (key >= other ? key : other) : (key <= other ? key : other);
      }
    }
    keys[tid] = key;
    __syncthreads();
  } else {
    // LDS bitonic up to 4096 (rare)
    for (int k2 = 2; k2 <= nsort; k2 <<= 1) {
      for (int j = k2 >> 1; j > 0; j >>= 1) {
        for (int i = tid; i < nsort; i += 1024) {
          int ij = i ^ j;
          if (ij > i) {
            u64 a = keys[i], bv = keys[ij];
            bool up = ((i & k2) == 0);
            if (up ? (a < bv) : (a > bv)) { keys[i] = bv; keys[ij] = a; }
          }
        }
        __syncthreads();
      }
    }
  }

  // write sorted keys, fetch boxes, init keep-words from validity
  if (tid < 512) {
    u64 key = (tid < K_PRE) ? keys[tid] : 0ULL;
    skey[(size_t)bc * 512 + tid] = key;
    float sc = __uint_as_float((unsigned)(key >> 32));
    unsigned anchor = 0xFFFFFFFFu - (unsigned)(key & 0xFFFFFFFFu);
    bool val = (tid < K_PRE) && (sc > SCORE_TH);
    if (!val || anchor >= NN) anchor = 0;
    float4 bx = *(const float4*)(boxes + ((size_t)b * NN + anchor) * 4);
    if (tid < K_PRE) {
      sboxg[(size_t)bc * K_PRE + tid] = bx;
      sarg[(size_t)bc * K_PRE + tid] = fmaxf(bx.z - bx.x, 0.0f) * fmaxf(bx.w - bx.y, 0.0f);
    }
    u64 bm = __ballot(val);
    if ((tid & 63) == 0) keepi[bc * 8 + (tid >> 6)] = bm;
  }
}

// ---- bitmatrix: grid (8, 160); block = 64 rows x 512 cols; 32 ballots/thread ----
__global__ __launch_bounds__(1024) void k_bitmat(const float4* __restrict__ sboxg,
                                                 const float* __restrict__ sarg, u64* __restrict__ sup) {
  __shared__ float4 rbox[64];
  __shared__ float rar[64];
  int bc = blockIdx.y, rch = blockIdx.x;
  int tid = threadIdx.x;
  int half = tid >> 9;          // 0: rows [0,32), 1: rows [32,64) of this chunk
  int j = tid & 511;
  int w = (tid >> 6) & 7;
  int lane = tid & 63;
  if (tid < 64) {
    int r = rch * 64 + tid;
    int rc = r < K_PRE ? r : 0;
    rbox[tid] = sboxg[(size_t)bc * K_PRE + rc];
    rar[tid] = sarg[(size_t)bc * K_PRE + rc];
  }
  __syncthreads();
  int jc = j < K_PRE ? j : 0;
  float4 bj = sboxg[(size_t)bc * K_PRE + jc];
  float aj = sarg[(size_t)bc * K_PRE + jc];
  bool jval = j < K_PRE;
  int i0 = rch * 64 + half * 32;
  u64 myword = 0;
  for (int k = 0; k < 32; ++k) {
    int i = i0 + k;
    float4 bi = rbox[half * 32 + k];   // broadcast (wave-uniform)
    float ai = rar[half * 32 + k];
    float iw = fmaxf(fminf(bi.z, bj.z) - fmaxf(bi.x, bj.x), 0.0f);
    float ih = fmaxf(fminf(bi.w, bj.w) - fmaxf(bi.y, bj.y), 0.0f);
    float inter = iw * ih;
    float denom = fmaxf(ai + aj - inter, 1e-8f);
    bool pred = jval && (j > i) && (inter / denom > NMS_THR);
    u64 msk = __ballot(pred);
    if (k == lane) myword = msk;       // lanes 0..31 capture rows i0..i0+31
  }
  int i = i0 + lane;
  if (lane < 32 && i < K_PRE) sup[(size_t)bc * 4096 + w * 512 + i] = myword;  // 256B/wave contiguous
}

// ---- sweep: rows in named registers; SPARSE greedy diagonal (r13, proven) ----
template<int W>
__device__ __forceinline__ void sweep_block(u64 r0, u64 r1, u64 r2_, u64 r3, u64 r4, u64 r5,
                                            u64 r6, u64 r7, u64* keepw, int lane) {
  u64 diag = (W == 0) ? r0 : (W == 1) ? r1 : (W == 2) ? r2_ : (W == 3) ? r3
           : (W == 4) ? r4 : (W == 5) ? r5 : (W == 6) ? r6 : r7;
  u64 nz = __ballot(diag != 0ULL);   // rows of this block that suppress in-block
  u64 kw = keepw[W];                 // wave-uniform LDS read
  u64 work = kw & nz;
  while (work) {
    int r = (int)__builtin_ctzll(work);
    unsigned lo = (unsigned)__builtin_amdgcn_readlane((int)(unsigned)(diag & 0xFFFFFFFFu), r);
    unsigned hi = (unsigned)__builtin_amdgcn_readlane((int)(unsigned)(diag >> 32), r);
    u64 dv = ((u64)hi << 32) | (u64)lo;   // bit r itself never set (j>i strict)
    kw &= ~dv;
    work &= work - 1ULL;   // clear processed row
    work &= kw;            // drop rows suppressed by it
  }
  // phase 2: apply kept rows of this block to later words via masked OR-reduce
  u64 msk = 0ULL - ((kw >> lane) & 1ULL);
#define RED(x) { x |= shflx64(x, 1); x |= shflx64(x, 2); x |= shflx64(x, 4); \
                 x |= shflx64(x, 8); x |= shflx64(x, 16); x |= shflx64(x, 32); }
  u64 a1 = r1 & msk, a2 = r2_ & msk, a3 = r3 & msk, a4 = r4 & msk,
      a5 = r5 & msk, a6 = r6 & msk, a7 = r7 & msk;
  if (W < 1) RED(a1);
  if (W < 2) RED(a2);
  if (W < 3) RED(a3);
  if (W < 4) RED(a4);
  if (W < 5) RED(a5);
  if (W < 6) RED(a6);
  if (W < 7) RED(a7);
#undef RED
  if (lane == 0) {
    keepw[W] = kw;
    if (W < 1) keepw[1] &= ~a1;
    if (W < 2) keepw[2] &= ~a2;
    if (W < 3) keepw[3] &= ~a3;
    if (W < 4) keepw[4] &= ~a4;
    if (W < 5) keepw[5] &= ~a5;
    if (W < 6) keepw[6] &= ~a6;
    if (W < 7) keepw[7] &= ~a7;
  }
}

__global__ __launch_bounds__(512) void k_sweep(const u64* __restrict__ sup, const u64* __restrict__ keepi,
                                               const u64* __restrict__ skey, u64* __restrict__ cselk,
                                               int* __restrict__ csela, int* __restrict__ ksel) {
  __shared__ u64 keepw[8];
  int bc = blockIdx.x;
  int c = bc % CLS;
  int tid = threadIdx.x;
  int wid = tid >> 6, lane = tid & 63;
  int row = wid * 64 + lane;  // 0..511; rows >=500 garbage but keep-bit-masked
  const u64* sb = sup + (size_t)bc * 4096;
  u64 r0 = sb[0 * 512 + row];
  u64 r1 = sb[1 * 512 + row];
  u64 r2_ = sb[2 * 512 + row];
  u64 r3 = sb[3 * 512 + row];
  u64 r4 = sb[4 * 512 + row];
  u64 r5 = sb[5 * 512 + row];
  u64 r6 = sb[6 * 512 + row];
  u64 r7 = sb[7 * 512 + row];
  if (tid < 8) keepw[tid] = keepi[bc * 8 + tid];
  __syncthreads();
  if (wid == 0) sweep_block<0>(r0, r1, r2_, r3, r4, r5, r6, r7, keepw, lane);
  __syncthreads();
  if (wid == 1) sweep_block<1>(r0, r1, r2_, r3, r4, r5, r6, r7, keepw, lane);
  __syncthreads();
  if (wid == 2) sweep_block<2>(r0, r1, r2_, r3, r4, r5, r6, r7, keepw, lane);
  __syncthreads();
  if (wid == 3) sweep_block<3>(r0, r1, r2_, r3, r4, r5, r6, r7, keepw, lane);
  __syncthreads();
  if (wid == 4) sweep_block<4>(r0, r1, r2_, r3, r4, r5, r6, r7, keepw, lane);
  __syncthreads();
  if (wid == 5) sweep_block<5>(r0, r1, r2_, r3, r4, r5, r6, r7, keepw, lane);
  __syncthreads();
  if (wid == 6) sweep_block<6>(r0, r1, r2_, r3, r4, r5, r6, r7, keepw, lane);
  __syncthreads();
  if (wid == 7) sweep_block<7>(r0, r1, r2_, r3, r4, r5, r6, r7, keepw, lane);
  __syncthreads();
  if (tid < 64) {
    int cnt = (tid < 8) ? __popcll(keepw[tid]) : 0;
    cnt += __shfl_xor(cnt, 1, 64);
    cnt += __shfl_xor(cnt, 2, 64);
    cnt += __shfl_xor(cnt, 4, 64);
    if (tid == 0) ksel[bc] = cnt > MAXDET ? MAXDET : cnt;
  }
  __syncthreads();
  if (tid < K_PRE) {
    int w = tid >> 6, bpos = tid & 63;
    u64 kw = keepw[w];
    if ((kw >> bpos) & 1ULL) {
      int rank = 0;
      for (int ww = 0; ww < w; ++ww) rank += __popcll(keepw[ww]);
      rank += __popcll(kw & ((1ULL << bpos) - 1ULL));
      if (rank < MAXDET) {
        u64 key = skey[(size_t)bc * 512 + tid];
        float sc = __uint_as_float((unsigned)(key >> 32));
        unsigned anchor = 0xFFFFFFFFu - (unsigned)(key & 0xFFFFFFFFu);
        if (anchor >= NN) anchor = 0;
        unsigned flat = (unsigned)(c * K_PRE + tid);
        cselk[(size_t)bc * MAXDET + rank] = ((u64)__float_as_uint(sc) << 32) | (u64)(0xFFFFFFFFu - flat);
        csela[(size_t)bc * MAXDET + rank] = (int)anchor;
      }
    }
  }
}

// ---- per-image: top-48-per-class truncate + 1024 bitonic -> exact global top-300 ----
// main path loads only 960+20 keys from global; the full skeym LDS table is populated
// ONLY inside the (rare, block-uniform) fallback branch.
__global__ __launch_bounds__(1024) void k_out(const float* __restrict__ boxes, const u64* __restrict__ cselk,
                                              const u64* __restrict__ skeyg, const int* __restrict__ csela,
                                              const int* __restrict__ ksel, float* __restrict__ out) {
  __shared__ u64 skeym[CLS][MAXDET];  // 48KB, fallback-only
  __shared__ int skc[CLS];
  __shared__ u64 skey49[CLS];
  __shared__ u64 carr[1024];          // 8KB: candidates + bitonic exchange buffer
  __shared__ int scond;
  __shared__ u64 sT;
  __shared__ int winc[MAXDET];
  __shared__ float winsc[MAXDET];
  int b = blockIdx.x, tid = threadIdx.x;
  if (tid < CLS) skc[tid] = ksel[b * CLS + tid];
  if (tid == 0) scond = 1;
  __syncthreads();
  // top-48 of each class direct from global -> 960 candidates, pad to 1024
  {
    u64 v = 0ULL;
    if (tid < CLS * 48) {
      int c = tid / 48, p = tid % 48;
      if (p < skc[c]) v = cselk[(size_t)(b * CLS + c) * MAXDET + p];
    }
    carr[tid] = v;
    if (tid < CLS) skey49[tid] = (skc[tid] > 48) ? cselk[(size_t)(b * CLS + tid) * MAXDET + 48] : 0ULL;
  }
  __syncthreads();
  {
    u64 key = carr[tid];
    __syncthreads();
    for (int k2 = 2; k2 <= 1024; k2 <<= 1) {
      for (int j = k2 >> 1; j > 0; j >>= 1) {
        u64 other;
        if (j >= 64) {
          carr[tid] = key; __syncthreads();
          other = carr[tid ^ j]; __syncthreads();
        } else {
          other = shflx64(key, j);
        }
        bool keepmax = (((tid & k2) == 0) == ((tid & j) == 0));
        key = keepmax ? (key >= other ? key : other) : (key <= other ? key : other);
      }
    }
    carr[tid] = key;
    __syncthreads();
  }
  if (tid == 0) sT = carr[MAXDET - 1];
  __syncthreads();
  if (tid < CLS) {
    if (skc[tid] > 48 && skey49[tid] >= sT) atomicAnd(&scond, 0);
  }
  __syncthreads();

  if (scond) {
    for (int i = tid; i < MAXDET; i += 1024) {
      u64 kk = carr[i];
      float4 bx; float sc, lb;
      if (kk == 0ULL) {
        bx = make_float4(-1.f, -1.f, -1.f, -1.f); sc = -1.f; lb = -1.f;
      } else {
        unsigned flat = 0xFFFFFFFFu - (unsigned)(kk & 0xFFFFFFFFu);
        int c = flat / K_PRE, pos = flat % K_PRE;
        u64 sk = skeyg[(size_t)(b * CLS + c) * 512 + pos];
        unsigned anchor = 0xFFFFFFFFu - (unsigned)(sk & 0xFFFFFFFFu);
        if (anchor >= NN) anchor = 0;
        bx = *(const float4*)(boxes + ((size_t)b * NN + anchor) * 4);
        sc = __uint_as_float((unsigned)(kk >> 32));
        lb = (float)(c - 1);  // reference: out_labels = fl - 1
      }
      *(float4*)(out + ((size_t)b * MAXDET + i) * 4) = bx;
      out[BB * MAXDET * 4 + b * MAXDET + i] = sc;
      out[BB * MAXDET * 4 + BB * MAXDET + b * MAXDET + i] = lb;
    }
    return;
  }

  // ---- fallback: load full per-class lists, serial tournament (rare; exact) ----
  for (int t = tid; t < CLS * MAXDET; t += 1024) {
    int c = t / MAXDET, p = t % MAXDET;
    skeym[c][p] = (p < skc[c]) ? cselk[(size_t)(b * CLS + c) * MAXDET + p] : 0ULL;
  }
  __syncthreads();
  if (tid < 64) {
    int lane = tid;
    u64 cur = 0, nxt = 0; int p = 0, kc = 0;
    if (lane < CLS) {
      kc = skc[lane];
      cur = kc > 0 ? skeym[lane][0] : 0ULL;
      nxt = kc > 1 ? skeym[lane][1] : 0ULL;
    }
    for (int i = 0; i < MAXDET; ++i) {
      u64 mx = cur;
#pragma unroll
      for (int off = 16; off >= 1; off >>= 1) {
        unsigned hi = __shfl_xor((int)(unsigned)(mx >> 32), off, 32);
        unsigned lo = __shfl_xor((int)(unsigned)(mx & 0xFFFFFFFFu), off, 32);
        u64 o = ((u64)hi << 32) | lo;
        if (o > mx) mx = o;
      }
      if (mx != 0ULL && cur == mx) {
        winc[i] = (lane << 16) | p;
        winsc[i] = __uint_as_float((unsigned)(mx >> 32));
        ++p;
        cur = nxt;
        nxt = (p + 1 < kc) ? skeym[lane][p + 1] : 0ULL;
      }
      if (mx == 0ULL && lane == 0) winc[i] = -1;
    }
  }
  __syncthreads();
  for (int i = tid; i < MAXDET; i += 1024) {
    int wc = winc[i];
    float4 bx; float sc, lb;
    if (wc < 0) {
      bx = make_float4(-1.f, -1.f, -1.f, -1.f); sc = -1.f; lb = -1.f;
    } else {
      int c = wc >> 16, p = wc & 0xFFFF;
      int anchor = csela[(size_t)(b * CLS + c) * MAXDET + p];
      bx = *(const float4*)(boxes + ((size_t)b * NN + anchor) * 4);
      sc = winsc[i];
      lb = (float)(c - 1);
    }
    *(float4*)(out + ((size_t)b * MAXDET + i) * 4) = bx;
    out[BB * MAXDET * 4 + b * MAXDET + i] = sc;
    out[BB * MAXDET * 4 + BB * MAXDET + b * MAXDET + i] = lb;
  }
}

extern "C" void kernel_launch(void* const* d_in, const int* in_sizes, int n_in,
                              void* d_out, int out_size, void* d_ws, size_t ws_size,
                              hipStream_t stream) {
  (void)in_sizes; (void)n_in; (void)out_size; (void)ws_size;
  const float* boxes = (const float*)d_in[0];
  const float* cls = (const float*)d_in[1];
  float* out = (float*)d_out;
  char* ws = (char*)d_ws;
  int* bcnt   = (int*)(ws + BCNT_OFF);
  u64* bdata  = (u64*)(ws + BDATA_OFF);
  u64* skey   = (u64*)(ws + SKEY_OFF);
  float4* sboxg = (float4*)(ws + SBOX_OFF);
  float* sarg = (float*)(ws + SAR_OFF);
  u64* keepi  = (u64*)(ws + KEEPI_OFF);
  u64* sup    = (u64*)(ws + SUP_OFF);
  u64* cselk  = (u64*)(ws + CSELK_OFF);
  int* csela  = (int*)(ws + CSELA_OFF);
  int* ksel   = (int*)(ws + KSEL_OFF);

  k_collect<<<dim3(CBLK, BB), CTHR, 0, stream>>>(cls, bcnt, bdata);
  k_sortgather<<<BB * CLS, 1024, 0, stream>>>(boxes, cls, bcnt, bdata, skey, sboxg, sarg, keepi);
  k_bitmat<<<dim3(8, BB * CLS), 1024, 0, stream>>>(sboxg, sarg, sup);
  k_sweep<<<BB * CLS, 512, 0, stream>>>(sup, keepi, skey, cselk, csela, ksel);
  k_out<<<BB, 1024, 0, stream>>>(boxes, cselk, skey, csela, ksel, out);
}

// Round 16
// 96.443 us; speedup vs baseline: 9.3392x; 1.0017x over previous
//
#include <hip/hip_runtime.h>
#include <stdint.h>

typedef unsigned long long u64;

#define BB 8
#define NN 200000
#define CLS 20
#define K_PRE 500
#define MAXDET 300
#define SCORE_TH 0.05f
#define NMS_THR 0.5f

#define NBINS 512
#define CAND_CAP 4096

// fast path: fixed conservative collect threshold (uniform scores -> ~842/class >> 500)
// exactness for arbitrary inputs preserved by the IN-BLOCK histogram fallback in k_sortgather.
#define T_COL 0.996f

// collect geometry: 256 blocks/image x 2 iters x 8 loads x 256 thr = 4096 float4/block
#define CBLK 256
#define CTHR 256
#define IMG_F4 1000000
#define ITERS 2
#define BCAP 16                  // per block-class staging (lambda ~3.5; overflow -> fallback)

static constexpr float BINSCALE = (float)NBINS / 0.95f;

// ws layout (bytes) -- NO region read before written within one launch sequence.
// (sup rows 500..511 read uninitialized but always masked by zero keep-bits.)
#define BCNT_OFF 0              // 2048*20*4 = 163840
#define BDATA_OFF 163840        // 2048*20*16*8 = 5242880 -> 5406720
#define SKEY_OFF 5406720        // 160*512*8 = 655360 -> 6062080
#define SBOX_OFF 6062080        // 160*500*16 = 1280000 -> 7342080
#define SAR_OFF  7342080        // 160*500*4 = 320000 -> 7662080
#define KEEPI_OFF 7662080       // 160*8*8 = 10240 -> 7672320
#define SUP_OFF  7672320        // 160*4096*8 = 5242880 -> 12915200
#define CSELK_OFF 12915200      // 160*300*8 = 384000 -> 13299200
#define CSELA_OFF 13299200      // 160*300*4 = 192000 -> 13491200
#define KSEL_OFF 13491200       // 640 -> 13491840

__device__ __forceinline__ int score_bin(float s) {
  int b = (int)((s - SCORE_TH) * BINSCALE);
  return b < 0 ? 0 : (b > NBINS - 1 ? NBINS - 1 : b);
}

__device__ __forceinline__ u64 shflx64(u64 v, int mask) {
  int hi = __shfl_xor((int)(unsigned)(v >> 32), mask, 64);
  int lo = __shfl_xor((int)(unsigned)(v & 0xFFFFFFFFu), mask, 64);
  return ((u64)(unsigned)hi << 32) | (unsigned)lo;
}

// ---- streaming pass: zero global atomics, LDS staging, per-block output region ----
__global__ __launch_bounds__(256) void k_collect(const float* __restrict__ cls,
                                                 int* __restrict__ bcnt, u64* __restrict__ bdata) {
  __shared__ u64 ldata[CLS][BCAP];   // 2.5KB
  __shared__ int lcnt[CLS];
  int tid = threadIdx.x;
  if (tid < CLS) lcnt[tid] = 0;
  __syncthreads();
  int blk = blockIdx.x, b = blockIdx.y;
  const float4* p = (const float4*)(cls + (size_t)b * IMG_F4 * 4);
  int base0 = blk * (ITERS * 8 * CTHR);
  bool full = (base0 + ITERS * 8 * CTHR) <= IMG_F4;

#define PROC(v, fidx) { \
    float m4_ = fmaxf(fmaxf((v).x, (v).y), fmaxf((v).z, (v).w)); \
    if (m4_ > T_COL) { \
      float vv_[4] = {(v).x, (v).y, (v).z, (v).w}; \
      _Pragma("unroll") \
      for (int e_ = 0; e_ < 4; ++e_) { \
        if (vv_[e_] > T_COL) { \
          int g_ = (fidx) * 4 + e_; \
          int c_ = g_ % CLS, a_ = g_ / CLS; \
          int li_ = atomicAdd(&lcnt[c_], 1); \
          if (li_ < BCAP) \
            ldata[c_][li_] = ((u64)__float_as_uint(vv_[e_]) << 32) | (u64)(0xFFFFFFFFu - (unsigned)a_); \
        } \
      } \
    } }

  for (int it = 0; it < ITERS; ++it) {
    int i0 = base0 + it * (8 * CTHR) + tid;
    if (full) {
      float4 v0 = p[i0];
      float4 v1 = p[i0 + 1 * CTHR];
      float4 v2 = p[i0 + 2 * CTHR];
      float4 v3 = p[i0 + 3 * CTHR];
      float4 v4 = p[i0 + 4 * CTHR];
      float4 v5 = p[i0 + 5 * CTHR];
      float4 v6 = p[i0 + 6 * CTHR];
      float4 v7 = p[i0 + 7 * CTHR];
      PROC(v0, i0);
      PROC(v1, i0 + 1 * CTHR);
      PROC(v2, i0 + 2 * CTHR);
      PROC(v3, i0 + 3 * CTHR);
      PROC(v4, i0 + 4 * CTHR);
      PROC(v5, i0 + 5 * CTHR);
      PROC(v6, i0 + 6 * CTHR);
      PROC(v7, i0 + 7 * CTHR);
    } else {
      for (int k = 0; k < 8; ++k) {
        int idx = i0 + k * CTHR;
        if (idx < IMG_F4) { float4 v = p[idx]; PROC(v, idx); }
      }
    }
  }
#undef PROC
  __syncthreads();
  int w = tid >> 6, lane = tid & 63;
  int gblk = b * CBLK + blk;
  for (int c = w; c < CLS; c += 4) {
    int cnt = lcnt[c];
    if (lane == 0) bcnt[gblk * CLS + c] = cnt;   // real count (may exceed BCAP -> fallback)
    int ns = cnt < BCAP ? cnt : BCAP;
    if (lane < ns) bdata[((size_t)(gblk * CLS + c)) * BCAP + lane] = ldata[c][lane];
  }
}

// ---- per-(b,c): validity check + gather (or in-block fallback) + exact top-500 sort ----
__global__ __launch_bounds__(1024) void k_sortgather(const float* __restrict__ boxes,
                                                     const float* __restrict__ cls,
                                                     const int* __restrict__ bcnt, const u64* __restrict__ bdata,
                                                     u64* __restrict__ skey, float4* __restrict__ sboxg,
                                                     float* __restrict__ sarg, u64* __restrict__ keepi) {
  __shared__ u64 keys[CAND_CAP];       // 32KB; [0..1023]/[1024..2047] double-buffer in fast path
  __shared__ int scnt[CBLK], soff[CBLK + 1];
  __shared__ int lh[NBINS];            // 2KB, fallback histogram
  __shared__ int sflag, sbin, scount;
  int bc = blockIdx.x;
  int b = bc / CLS, c = bc % CLS;
  int tid = threadIdx.x;
  if (tid == 0) { sflag = 0; scount = 0; }
  __syncthreads();
  if (tid < CBLK) {
    int v = bcnt[(b * CBLK + tid) * CLS + c];
    scnt[tid] = v;
    if (v > BCAP) atomicOr(&sflag, 1);
  }
  __syncthreads();
  // single-wave exclusive scan of 256 counts (4 per lane)
  if (tid < 64) {
    int a0 = scnt[4 * tid], a1 = scnt[4 * tid + 1], a2 = scnt[4 * tid + 2], a3 = scnt[4 * tid + 3];
    int tot = a0 + a1 + a2 + a3;
    int s = tot;
#pragma unroll
    for (int o = 1; o < 64; o <<= 1) {
      int t2 = __shfl_up(s, o, 64);
      if ((int)tid >= o) s += t2;
    }
    int excl = s - tot;
    soff[4 * tid] = excl;
    soff[4 * tid + 1] = excl + a0;
    soff[4 * tid + 2] = excl + a0 + a1;
    soff[4 * tid + 3] = excl + a0 + a1 + a2;
    if (tid == 63) soff[CBLK] = s;
  }
  __syncthreads();
  int total = soff[CBLK];
  bool fallback = (sflag != 0) || (total > CAND_CAP) || (total < K_PRE);
  int m;
  if (!fallback) {
    m = total;
    for (int e = tid; e < CBLK * BCAP; e += 1024) {
      int j = e >> 4, s = e & (BCAP - 1);
      if (s < scnt[j]) keys[soff[j] + s] = bdata[((size_t)((b * CBLK + j) * CLS + c)) * BCAP + s];
    }
  } else {
    // in-block exact fallback: histogram over this (b,c) column, threshold, collect.
    for (int i = tid; i < NBINS; i += 1024) lh[i] = 0;
    __syncthreads();
    for (int a = tid; a < NN; a += 1024) {
      float s = cls[((size_t)b * NN + a) * CLS + c];
      if (s > SCORE_TH) atomicAdd(&lh[score_bin(s)], 1);
    }
    __syncthreads();
    if (tid == 0) {
      int sum = 0, bin = 0;
      for (int i = NBINS - 1; i >= 0; --i) {
        sum += lh[i];
        if (sum >= K_PRE) { bin = i; break; }
      }
      sbin = bin;
    }
    __syncthreads();
    int bin = sbin;
    for (int a = tid; a < NN; a += 1024) {
      float s = cls[((size_t)b * NN + a) * CLS + c];
      if (s > SCORE_TH && score_bin(s) >= bin) {
        int pos = atomicAdd(&scount, 1);
        if (pos < CAND_CAP)
          keys[pos] = ((u64)__float_as_uint(s) << 32) | (u64)(0xFFFFFFFFu - (unsigned)a);
      }
    }
    __syncthreads();
    m = scount; if (m > CAND_CAP) m = CAND_CAP;
  }
  int nsort = 1024; while (nsort < m) nsort <<= 1;
  for (int i = m + tid; i < nsort; i += 1024) keys[i] = 0ULL;
  __syncthreads();

  if (nsort <= 1024) {
    // in-register bitonic, descending; shfl_xor j<64, DOUBLE-BUFFERED LDS exchange
    // j>=64 (1 barrier/round: next round writes the other buffer, killing the WAR sync).
    u64 key = keys[tid];
    int cur = 0;
    for (int k2 = 2; k2 <= 1024; k2 <<= 1) {
      for (int j = k2 >> 1; j > 0; j >>= 1) {
        u64 other;
        if (j >= 64) {
          keys[cur * 1024 + tid] = key;
          __syncthreads();
          other = keys[cur * 1024 + (tid ^ j)];
          cur ^= 1;
        } else {
          other = shflx64(key, j);
        }
        bool keepmax = (((tid & k2) == 0) == ((tid & j) == 0));
        key = keepmax ? (key >= other ? key : other) : (key <= other ? key : other);
      }
    }
    keys[tid] = key;   // own slot; extract below reads own slot only
    __syncthreads();
  } else {
    // LDS bitonic up to 4096 (rare)
    for (int k2 = 2; k2 <= nsort; k2 <<= 1) {
      for (int j = k2 >> 1; j > 0; j >>= 1) {
        for (int i = tid; i < nsort; i += 1024) {
          int ij = i ^ j;
          if (ij > i) {
            u64 a = keys[i], bv = keys[ij];
            bool up = ((i & k2) == 0);
            if (up ? (a < bv) : (a > bv)) { keys[i] = bv; keys[ij] = a; }
          }
        }
        __syncthreads();
      }
    }
  }

  // write sorted keys, fetch boxes, init keep-words from validity
  if (tid < 512) {
    u64 key = (tid < K_PRE) ? keys[tid] : 0ULL;
    skey[(size_t)bc * 512 + tid] = key;
    float sc = __uint_as_float((unsigned)(key >> 32));
    unsigned anchor = 0xFFFFFFFFu - (unsigned)(key & 0xFFFFFFFFu);
    bool val = (tid < K_PRE) && (sc > SCORE_TH);
    if (!val || anchor >= NN) anchor = 0;
    float4 bx = *(const float4*)(boxes + ((size_t)b * NN + anchor) * 4);
    if (tid < K_PRE) {
      sboxg[(size_t)bc * K_PRE + tid] = bx;
      sarg[(size_t)bc * K_PRE + tid] = fmaxf(bx.z - bx.x, 0.0f) * fmaxf(bx.w - bx.y, 0.0f);
    }
    u64 bm = __ballot(val);
    if ((tid & 63) == 0) keepi[bc * 8 + (tid >> 6)] = bm;
  }
}

// ---- bitmatrix: grid (8, 160); block = 64 rows x 512 cols; 32 ballots/thread ----
__global__ __launch_bounds__(1024) void k_bitmat(const float4* __restrict__ sboxg,
                                                 const float* __restrict__ sarg, u64* __restrict__ sup) {
  __shared__ float4 rbox[64];
  __shared__ float rar[64];
  int bc = blockIdx.y, rch = blockIdx.x;
  int tid = threadIdx.x;
  int half = tid >> 9;          // 0: rows [0,32), 1: rows [32,64) of this chunk
  int j = tid & 511;
  int w = (tid >> 6) & 7;
  int lane = tid & 63;
  if (tid < 64) {
    int r = rch * 64 + tid;
    int rc = r < K_PRE ? r : 0;
    rbox[tid] = sboxg[(size_t)bc * K_PRE + rc];
    rar[tid] = sarg[(size_t)bc * K_PRE + rc];
  }
  __syncthreads();
  int jc = j < K_PRE ? j : 0;
  float4 bj = sboxg[(size_t)bc * K_PRE + jc];
  float aj = sarg[(size_t)bc * K_PRE + jc];
  bool jval = j < K_PRE;
  int i0 = rch * 64 + half * 32;
  u64 myword = 0;
  for (int k = 0; k < 32; ++k) {
    int i = i0 + k;
    float4 bi = rbox[half * 32 + k];   // broadcast (wave-uniform)
    float ai = rar[half * 32 + k];
    float iw = fmaxf(fminf(bi.z, bj.z) - fmaxf(bi.x, bj.x), 0.0f);
    float ih = fmaxf(fminf(bi.w, bj.w) - fmaxf(bi.y, bj.y), 0.0f);
    float inter = iw * ih;
    float denom = fmaxf(ai + aj - inter, 1e-8f);
    bool pred = jval && (j > i) && (inter / denom > NMS_THR);
    u64 msk = __ballot(pred);
    if (k == lane) myword = msk;       // lanes 0..31 capture rows i0..i0+31
  }
  int i = i0 + lane;
  if (lane < 32 && i < K_PRE) sup[(size_t)bc * 4096 + w * 512 + i] = myword;  // 256B/wave contiguous
}

// ---- sweep: rows in named registers; SPARSE greedy diagonal (r13, proven) ----
template<int W>
__device__ __forceinline__ void sweep_block(u64 r0, u64 r1, u64 r2_, u64 r3, u64 r4, u64 r5,
                                            u64 r6, u64 r7, u64* keepw, int lane) {
  u64 diag = (W == 0) ? r0 : (W == 1) ? r1 : (W == 2) ? r2_ : (W == 3) ? r3
           : (W == 4) ? r4 : (W == 5) ? r5 : (W == 6) ? r6 : r7;
  u64 nz = __ballot(diag != 0ULL);   // rows of this block that suppress in-block
  u64 kw = keepw[W];                 // wave-uniform LDS read
  u64 work = kw & nz;
  while (work) {
    int r = (int)__builtin_ctzll(work);
    unsigned lo = (unsigned)__builtin_amdgcn_readlane((int)(unsigned)(diag & 0xFFFFFFFFu), r);
    unsigned hi = (unsigned)__builtin_amdgcn_readlane((int)(unsigned)(diag >> 32), r);
    u64 dv = ((u64)hi << 32) | (u64)lo;   // bit r itself never set (j>i strict)
    kw &= ~dv;
    work &= work - 1ULL;   // clear processed row
    work &= kw;            // drop rows suppressed by it
  }
  // phase 2: apply kept rows of this block to later words via masked OR-reduce
  u64 msk = 0ULL - ((kw >> lane) & 1ULL);
#define RED(x) { x |= shflx64(x, 1); x |= shflx64(x, 2); x |= shflx64(x, 4); \
                 x |= shflx64(x, 8); x |= shflx64(x, 16); x |= shflx64(x, 32); }
  u64 a1 = r1 & msk, a2 = r2_ & msk, a3 = r3 & msk, a4 = r4 & msk,
      a5 = r5 & msk, a6 = r6 & msk, a7 = r7 & msk;
  if (W < 1) RED(a1);
  if (W < 2) RED(a2);
  if (W < 3) RED(a3);
  if (W < 4) RED(a4);
  if (W < 5) RED(a5);
  if (W < 6) RED(a6);
  if (W < 7) RED(a7);
#undef RED
  if (lane == 0) {
    keepw[W] = kw;
    if (W < 1) keepw[1] &= ~a1;
    if (W < 2) keepw[2] &= ~a2;
    if (W < 3) keepw[3] &= ~a3;
    if (W < 4) keepw[4] &= ~a4;
    if (W < 5) keepw[5] &= ~a5;
    if (W < 6) keepw[6] &= ~a6;
    if (W < 7) keepw[7] &= ~a7;
  }
}

__global__ __launch_bounds__(512) void k_sweep(const u64* __restrict__ sup, const u64* __restrict__ keepi,
                                               const u64* __restrict__ skey, u64* __restrict__ cselk,
                                               int* __restrict__ csela, int* __restrict__ ksel) {
  __shared__ u64 keepw[8];
  int bc = blockIdx.x;
  int c = bc % CLS;
  int tid = threadIdx.x;
  int wid = tid >> 6, lane = tid & 63;
  int row = wid * 64 + lane;  // 0..511; rows >=500 garbage but keep-bit-masked
  const u64* sb = sup + (size_t)bc * 4096;
  u64 r0 = sb[0 * 512 + row];
  u64 r1 = sb[1 * 512 + row];
  u64 r2_ = sb[2 * 512 + row];
  u64 r3 = sb[3 * 512 + row];
  u64 r4 = sb[4 * 512 + row];
  u64 r5 = sb[5 * 512 + row];
  u64 r6 = sb[6 * 512 + row];
  u64 r7 = sb[7 * 512 + row];
  if (tid < 8) keepw[tid] = keepi[bc * 8 + tid];
  __syncthreads();
  if (wid == 0) sweep_block<0>(r0, r1, r2_, r3, r4, r5, r6, r7, keepw, lane);
  __syncthreads();
  if (wid == 1) sweep_block<1>(r0, r1, r2_, r3, r4, r5, r6, r7, keepw, lane);
  __syncthreads();
  if (wid == 2) sweep_block<2>(r0, r1, r2_, r3, r4, r5, r6, r7, keepw, lane);
  __syncthreads();
  if (wid == 3) sweep_block<3>(r0, r1, r2_, r3, r4, r5, r6, r7, keepw, lane);
  __syncthreads();
  if (wid == 4) sweep_block<4>(r0, r1, r2_, r3, r4, r5, r6, r7, keepw, lane);
  __syncthreads();
  if (wid == 5) sweep_block<5>(r0, r1, r2_, r3, r4, r5, r6, r7, keepw, lane);
  __syncthreads();
  if (wid == 6) sweep_block<6>(r0, r1, r2_, r3, r4, r5, r6, r7, keepw, lane);
  __syncthreads();
  if (wid == 7) sweep_block<7>(r0, r1, r2_, r3, r4, r5, r6, r7, keepw, lane);
  __syncthreads();
  if (tid < 64) {
    int cnt = (tid < 8) ? __popcll(keepw[tid]) : 0;
    cnt += __shfl_xor(cnt, 1, 64);
    cnt += __shfl_xor(cnt, 2, 64);
    cnt += __shfl_xor(cnt, 4, 64);
    if (tid == 0) ksel[bc] = cnt > MAXDET ? MAXDET : cnt;
  }
  __syncthreads();
  if (tid < K_PRE) {
    int w = tid >> 6, bpos = tid & 63;
    u64 kw = keepw[w];
    if ((kw >> bpos) & 1ULL) {
      int rank = 0;
      for (int ww = 0; ww < w; ++ww) rank += __popcll(keepw[ww]);
      rank += __popcll(kw & ((1ULL << bpos) - 1ULL));
      if (rank < MAXDET) {
        u64 key = skey[(size_t)bc * 512 + tid];
        float sc = __uint_as_float((unsigned)(key >> 32));
        unsigned anchor = 0xFFFFFFFFu - (unsigned)(key & 0xFFFFFFFFu);
        if (anchor >= NN) anchor = 0;
        unsigned flat = (unsigned)(c * K_PRE + tid);
        cselk[(size_t)bc * MAXDET + rank] = ((u64)__float_as_uint(sc) << 32) | (u64)(0xFFFFFFFFu - flat);
        csela[(size_t)bc * MAXDET + rank] = (int)anchor;
      }
    }
  }
}

// ---- per-image: top-48-per-class truncate + 1024 bitonic -> exact global top-300 ----
// main path loads only 960+20 keys from global; full skeym LDS table fallback-only.
__global__ __launch_bounds__(1024) void k_out(const float* __restrict__ boxes, const u64* __restrict__ cselk,
                                              const u64* __restrict__ skeyg, const int* __restrict__ csela,
                                              const int* __restrict__ ksel, float* __restrict__ out) {
  __shared__ u64 skeym[CLS][MAXDET];  // 48KB, fallback-only
  __shared__ int skc[CLS];
  __shared__ u64 skey49[CLS];
  __shared__ u64 carr[2048];          // 16KB: double-buffered bitonic exchange
  __shared__ int scond;
  __shared__ u64 sT;
  __shared__ int winc[MAXDET];
  __shared__ float winsc[MAXDET];
  int b = blockIdx.x, tid = threadIdx.x;
  if (tid < CLS) skc[tid] = ksel[b * CLS + tid];
  if (tid == 0) scond = 1;
  __syncthreads();
  // top-48 of each class direct from global -> 960 candidates, pad to 1024
  u64 key = 0ULL;
  {
    if (tid < CLS * 48) {
      int c = tid / 48, p = tid % 48;
      if (p < skc[c]) key = cselk[(size_t)(b * CLS + c) * MAXDET + p];
    }
    if (tid < CLS) skey49[tid] = (skc[tid] > 48) ? cselk[(size_t)(b * CLS + tid) * MAXDET + 48] : 0ULL;
  }
  // in-register bitonic 1024, descending; double-buffered LDS exchange (1 barrier/round)
  {
    int cur = 0;
    for (int k2 = 2; k2 <= 1024; k2 <<= 1) {
      for (int j = k2 >> 1; j > 0; j >>= 1) {
        u64 other;
        if (j >= 64) {
          carr[cur * 1024 + tid] = key;
          __syncthreads();
          other = carr[cur * 1024 + (tid ^ j)];
          cur ^= 1;
        } else {
          other = shflx64(key, j);
        }
        bool keepmax = (((tid & k2) == 0) == ((tid & j) == 0));
        key = keepmax ? (key >= other ? key : other) : (key <= other ? key : other);
      }
    }
    carr[tid] = key;
    __syncthreads();
  }
  if (tid == 0) sT = carr[MAXDET - 1];
  __syncthreads();
  if (tid < CLS) {
    if (skc[tid] > 48 && skey49[tid] >= sT) atomicAnd(&scond, 0);
  }
  __syncthreads();

  if (scond) {
    for (int i = tid; i < MAXDET; i += 1024) {
      u64 kk = carr[i];
      float4 bx; float sc, lb;
      if (kk == 0ULL) {
        bx = make_float4(-1.f, -1.f, -1.f, -1.f); sc = -1.f; lb = -1.f;
      } else {
        unsigned flat = 0xFFFFFFFFu - (unsigned)(kk & 0xFFFFFFFFu);
        int c = flat / K_PRE, pos = flat % K_PRE;
        u64 sk = skeyg[(size_t)(b * CLS + c) * 512 + pos];
        unsigned anchor = 0xFFFFFFFFu - (unsigned)(sk & 0xFFFFFFFFu);
        if (anchor >= NN) anchor = 0;
        bx = *(const float4*)(boxes + ((size_t)b * NN + anchor) * 4);
        sc = __uint_as_float((unsigned)(kk >> 32));
        lb = (float)(c - 1);  // reference: out_labels = fl - 1
      }
      *(float4*)(out + ((size_t)b * MAXDET + i) * 4) = bx;
      out[BB * MAXDET * 4 + b * MAXDET + i] = sc;
      out[BB * MAXDET * 4 + BB * MAXDET + b * MAXDET + i] = lb;
    }
    return;
  }

  // ---- fallback: load full per-class lists, serial tournament (rare; exact) ----
  for (int t = tid; t < CLS * MAXDET; t += 1024) {
    int c = t / MAXDET, p = t % MAXDET;
    skeym[c][p] = (p < skc[c]) ? cselk[(size_t)(b * CLS + c) * MAXDET + p] : 0ULL;
  }
  __syncthreads();
  if (tid < 64) {
    int lane = tid;
    u64 cur = 0, nxt = 0; int p = 0, kc = 0;
    if (lane < CLS) {
      kc = skc[lane];
      cur = kc > 0 ? skeym[lane][0] : 0ULL;
      nxt = kc > 1 ? skeym[lane][1] : 0ULL;
    }
    for (int i = 0; i < MAXDET; ++i) {
      u64 mx = cur;
#pragma unroll
      for (int off = 16; off >= 1; off >>= 1) {
        unsigned hi = __shfl_xor((int)(unsigned)(mx >> 32), off, 32);
        unsigned lo = __shfl_xor((int)(unsigned)(mx & 0xFFFFFFFFu), off, 32);
        u64 o = ((u64)hi << 32) | lo;
        if (o > mx) mx = o;
      }
      if (mx != 0ULL && cur == mx) {
        winc[i] = (lane << 16) | p;
        winsc[i] = __uint_as_float((unsigned)(mx >> 32));
        ++p;
        cur = nxt;
        nxt = (p + 1 < kc) ? skeym[lane][p + 1] : 0ULL;
      }
      if (mx == 0ULL && lane == 0) winc[i] = -1;
    }
  }
  __syncthreads();
  for (int i = tid; i < MAXDET; i += 1024) {
    int wc = winc[i];
    float4 bx; float sc, lb;
    if (wc < 0) {
      bx = make_float4(-1.f, -1.f, -1.f, -1.f); sc = -1.f; lb = -1.f;
    } else {
      int c = wc >> 16, p = wc & 0xFFFF;
      int anchor = csela[(size_t)(b * CLS + c) * MAXDET + p];
      bx = *(const float4*)(boxes + ((size_t)b * NN + anchor) * 4);
      sc = winsc[i];
      lb = (float)(c - 1);
    }
    *(float4*)(out + ((size_t)b * MAXDET + i) * 4) = bx;
    out[BB * MAXDET * 4 + b * MAXDET + i] = sc;
    out[BB * MAXDET * 4 + BB * MAXDET + b * MAXDET + i] = lb;
  }
}

extern "C" void kernel_launch(void* const* d_in, const int* in_sizes, int n_in,
                              void* d_out, int out_size, void* d_ws, size_t ws_size,
                              hipStream_t stream) {
  (void)in_sizes; (void)n_in; (void)out_size; (void)ws_size;
  const float* boxes = (const float*)d_in[0];
  const float* cls = (const float*)d_in[1];
  float* out = (float*)d_out;
  char* ws = (char*)d_ws;
  int* bcnt   = (int*)(ws + BCNT_OFF);
  u64* bdata  = (u64*)(ws + BDATA_OFF);
  u64* skey   = (u64*)(ws + SKEY_OFF);
  float4* sboxg = (float4*)(ws + SBOX_OFF);
  float* sarg = (float*)(ws + SAR_OFF);
  u64* keepi  = (u64*)(ws + KEEPI_OFF);
  u64* sup    = (u64*)(ws + SUP_OFF);
  u64* cselk  = (u64*)(ws + CSELK_OFF);
  int* csela  = (int*)(ws + CSELA_OFF);
  int* ksel   = (int*)(ws + KSEL_OFF);

  k_collect<<<dim3(CBLK, BB), CTHR, 0, stream>>>(cls, bcnt, bdata);
  k_sortgather<<<BB * CLS, 1024, 0, stream>>>(boxes, cls, bcnt, bdata, skey, sboxg, sarg, keepi);
  k_bitmat<<<dim3(8, BB * CLS), 1024, 0, stream>>>(sboxg, sarg, sup);
  k_sweep<<<BB * CLS, 512, 0, stream>>>(sup, keepi, skey, cselk, csela, ksel);
  k_out<<<BB, 1024, 0, stream>>>(boxes, cselk, skey, csela, ksel, out);
}